// Round 9
// baseline (509.655 us; speedup 1.0000x reference)
//
#include <hip/hip_runtime.h>

namespace {
typedef float v2f __attribute__((ext_vector_type(2)));
typedef unsigned u32x2 __attribute__((ext_vector_type(2)));
constexpr int kB = 256;
constexpr int kS = 2048;
constexpr int kV = 10;
constexpr int kE = 32;
constexpr int kH = 64;
constexpr int kO = 10;
constexpr int kT = 16;      // steps per tile
constexpr int kPad = 68;    // LDS row stride in floats (272 B, 16B-aligned)
constexpr int kTiles = kS / kT;   // 128
// Fold tanh's 2x and log2(e) into weights: s = kC*(xw + h.Wh + b), e^{2p} = 2^s
constexpr float kC = 2.885390081777927f;   // 2*log2(e)

__device__ __forceinline__ float step_tanh(float s) {
    s = __builtin_amdgcn_fmed3f(s, -26.f, 26.f);
    float e = __builtin_amdgcn_exp2f(s);
    float r = __builtin_amdgcn_rcpf(e + 1.f);
    return fmaf(-2.f, r, 1.f);              // tanh = 1 - 2/(e^{2p}+1)
}

// l <-> l^32 value fetch on the VALU pipe — R8-HW-PROVEN primitive.
__device__ __forceinline__ float swap32(float p) {
    u32x2 r = __builtin_amdgcn_permlane32_swap(__float_as_uint(p),
                                               __float_as_uint(p),
                                               false, false);
    return (__uint_as_float(r.x) + __uint_as_float(r.y)) - p;
}

// sum with l^16 partner: p + p[l^16].
#if __has_builtin(__builtin_amdgcn_permlane16_swap)
// permlane16_swap exchanges complementary 16-groups between its two operands;
// with both = p, the two results jointly hold {p[l], p[l^16]} at every lane
// (same duplication argument HW-verified for swap32 in R8), so their sum is
// p + p[l^16] directly (the -p cancels).
__device__ __forceinline__ float sum16(float p) {
    u32x2 r = __builtin_amdgcn_permlane16_swap(__float_as_uint(p),
                                               __float_as_uint(p),
                                               false, false);
    return __uint_as_float(r.x) + __uint_as_float(r.y);
}
#else
// Fallback: ds_swizzle BitMode XOR-16 (ISA doc: offset=(xor<<10)|(or<<5)|and).
__device__ __forceinline__ float sum16(float p) {
    float o = __int_as_float(
        __builtin_amdgcn_ds_swizzle(__float_as_int(p), 0x401F));
    return p + o;
}
#endif

__device__ __forceinline__ void do_logits(const float* __restrict__ hb,
                                          const float (* __restrict__ WdT)[kPad],
                                          const float* __restrict__ bdL,
                                          float* __restrict__ out, int obase, int l)
{
    #pragma unroll
    for (int r = 0; r < 3; ++r) {
        int f = r * 64 + l;                  // flat (t_local, o), 160 total
        if (f < kT * kO) {
            int tl = f / kO;
            int o  = f - tl * kO;
            const float4* hb4 = reinterpret_cast<const float4*>(hb + tl * kPad);
            const float4* wd4 = reinterpret_cast<const float4*>(&WdT[o][0]);
            float a0 = bdL[o], a1 = 0.f, a2 = 0.f, a3 = 0.f;
            #pragma unroll
            for (int c = 0; c < kH / 4; ++c) {
                float4 h4 = hb4[c];
                float4 w4 = wd4[c];
                a0 = fmaf(h4.x, w4.x, a0);
                a1 = fmaf(h4.y, w4.y, a1);
                a2 = fmaf(h4.z, w4.z, a2);
                a3 = fmaf(h4.w, w4.w, a3);
            }
            out[obase + f] = (a0 + a1) + (a2 + a3);   // coalesced
        }
    }
}

// Wave 0: serial recurrence with ZERO LDS on the chain's broadcast path.
// 4-way split-K: lane l (row q=l>>4, col b=l&15) accumulates partials for the
// 4 outputs {b+16c} over its OWN ROW's k-range [16q,16q+16) — those 16 h
// values are reached by DPP row_ror rotations of the h register (pure VALU).
// Rotation->source-lane mapping is SELF-CALIBRATED at setup by probing
// mov_dpp(lane_id), and weights are loaded to match — immune to ROR-direction
// convention. Combine: T[c] = own+l^16 partner row-pair sum (sum16), then
// y[l] = T[q] + T[q^2 from l^32] (swap32, R8-proven) + xw.
// The h-history ds_write remains but nothing on the chain reads it (wave 1
// logits only). Chain DS ops: TT read + write = 2 (was 10 in R8).
// Wave 1: logits for the previous tile from the double-buffered h history.
__global__ __launch_bounds__(128, 1)
void rnn_fused(const int* __restrict__ num1, const int* __restrict__ num2,
               const float* __restrict__ embed, const float* __restrict__ Wx,
               const float* __restrict__ Wh, const float* __restrict__ bias,
               const float* __restrict__ Wd, const float* __restrict__ bd,
               float* __restrict__ out)
{
    const int row = blockIdx.x;   // one sequence per block
    const int tid = threadIdx.x;
    const int w   = tid >> 6;     // 0 = recurrence wave, 1 = logits wave
    const int l   = tid & 63;     // lane owns hidden unit l
    const int b   = l & 15;       // column within row
    const int q   = l >> 4;       // 16-lane row = this lane's k-quarter

    __shared__ __align__(16) float TT[kV * kV][kH];     // kC*(xw+b), 100 rows
    __shared__ __align__(16) float hbuf[2][kT][kPad];   // double-buffered h history
    __shared__ __align__(16) float WdT[kO][kPad];
    __shared__ float bdL[kO];

    // rotation i weights: wA[i] = kC*Wh[src_i][{b, b+16}], wB[i] = ...{b+32, b+48}
    v2f wA[16], wB[16];
    float h = 0.f;
    int idx_next = 0;
    bool qb0 = false, qb1 = false;
    const int lane16 = b;
    const int nb = row * kS;
    const int orow = row * (kS * kO);

    if (w == 0) {
        // ---- one-time setup: input-projection table ----
        float wxc[2 * kE];
        #pragma unroll
        for (int k = 0; k < 2 * kE; ++k) wxc[k] = Wx[k * kH + l];  // Wx column l
        float bj = bias[l];
        float t1[kV], t2[kV];
        #pragma unroll
        for (int v = 0; v < kV; ++v) {
            float a0 = 0.f, a1 = 0.f;
            #pragma unroll
            for (int k = 0; k < kE; ++k) {
                float e = embed[v * kE + k];   // lane-uniform -> s_load
                a0 = fmaf(e, wxc[k], a0);
                a1 = fmaf(e, wxc[kE + k], a1);
            }
            t1[v] = a0; t2[v] = a1;
        }
        #pragma unroll
        for (int v1 = 0; v1 < kV; ++v1)
            #pragma unroll
            for (int v2 = 0; v2 < kV; ++v2)
                TT[v1 * kV + v2][l] = kC * (t1[v1] + t2[v2] + bj);

        // ---- self-calibrated DPP rotation -> weight tables ----
        #define SETW(i, SRC)                                                \
            do { int s_ = (SRC);                                            \
                 const float* p_ = Wh + s_ * kH + b;                        \
                 wA[i].x = kC * p_[0];  wA[i].y = kC * p_[16];              \
                 wB[i].x = kC * p_[32]; wB[i].y = kC * p_[48]; } while (0)
        SETW(0, l);
        #define SETR(i) SETW(i, __builtin_amdgcn_mov_dpp(l, 0x120 + i, 0xf, 0xf, false))
        SETR(1);  SETR(2);  SETR(3);  SETR(4);  SETR(5);
        SETR(6);  SETR(7);  SETR(8);  SETR(9);  SETR(10);
        SETR(11); SETR(12); SETR(13); SETR(14); SETR(15);
        #undef SETR
        #undef SETW

        qb0 = (q & 1) != 0;
        qb1 = (q & 2) != 0;
        idx_next = num1[nb + lane16] * kV + num2[nb + lane16];   // tile 0 idx
        __builtin_amdgcn_s_setprio(1);   // favor the chain wave in arbitration
    } else {
        #pragma unroll
        for (int o = 0; o < kO; ++o) WdT[o][l] = Wd[l * kO + o];
        if (l < kO) bdL[l] = bd[l];
    }
    __syncthreads();

    for (int ti = 0; ti < kTiles; ++ti) {
        if (w == 0) {
            const int idxv = idx_next;
            if (ti + 1 < kTiles) {
                int tt = nb + (ti + 1) * kT + lane16;
                idx_next = num1[tt] * kV + num2[tt];   // prefetch next tile idx
            }
            float* curBase = &hbuf[ti & 1][0][0];
            #pragma unroll 1
            for (int tl = 0; tl < kT; ++tl) {
                const int sidx = __builtin_amdgcn_readlane(idxv, tl); // dyn lane
                const float xwv = TT[sidx][l];   // only chain-side DS read
                // MAC block: 16 rotations x 4 outputs, even/odd acc chains
                v2f aA0, aA1, aB0, aB1;
                { v2f h2; h2.x = h; h2.y = h;                    // i = 0
                  aA0 = h2 * wA[0]; aB0 = h2 * wB[0];
                  aA1 = (v2f){0.f, 0.f}; aB1 = (v2f){0.f, 0.f}; }
                #define MACI(i, AA, BB)                                     \
                    do { float hr_ = __int_as_float(__builtin_amdgcn_mov_dpp( \
                             __float_as_int(h), 0x120 + i, 0xf, 0xf, false)); \
                         v2f h2_; h2_.x = hr_; h2_.y = hr_;                 \
                         AA = h2_ * wA[i] + AA;                             \
                         BB = h2_ * wB[i] + BB; } while (0)
                MACI(1,  aA1, aB1); MACI(2,  aA0, aB0); MACI(3,  aA1, aB1);
                MACI(4,  aA0, aB0); MACI(5,  aA1, aB1); MACI(6,  aA0, aB0);
                MACI(7,  aA1, aB1); MACI(8,  aA0, aB0); MACI(9,  aA1, aB1);
                MACI(10, aA0, aB0); MACI(11, aA1, aB1); MACI(12, aA0, aB0);
                MACI(13, aA1, aB1); MACI(14, aA0, aB0); MACI(15, aA1, aB1);
                #undef MACI
                v2f a01 = aA0 + aA1;   // partials: outputs {b, b+16},   row q
                v2f a23 = aB0 + aB1;   // partials: outputs {b+32, b+48}, row q
                // stage 1: + partner row (l^16) -> rows {q, q^1}
                float T0 = sum16(a01.x);
                float T1 = sum16(a01.y);
                float T2 = sum16(a23.x);
                float T3 = sum16(a23.y);
                // stage 2: pick T[q] and T[q^2]; fetch partner's via l^32
                float sA = qb0 ? T1 : T0;
                float sB = qb0 ? T3 : T2;
                float Tq  = qb1 ? sB : sA;
                float Tq2 = qb1 ? sA : sB;
                float oth = swap32(Tq2);     // = T_{l^32}[q], rows {q^2, q^3}
                h = step_tanh((Tq + oth) + xwv);
                curBase[tl * kPad + l] = h;  // history for wave 1 (off-chain)
            }
        } else if (ti > 0) {
            do_logits(&hbuf[(ti - 1) & 1][0][0], WdT, bdL, out,
                      orow + (ti - 1) * kT * kO, l);
        }
        __syncthreads();   // publish tile ti history / retire tile ti-1 reads
    }
    if (w == 1)
        do_logits(&hbuf[(kTiles - 1) & 1][0][0], WdT, bdL, out,
                  orow + (kS - kT) * kO, l);
}
} // namespace

extern "C" void kernel_launch(void* const* d_in, const int* in_sizes, int n_in,
                              void* d_out, int out_size, void* d_ws, size_t ws_size,
                              hipStream_t stream) {
    (void)in_sizes; (void)n_in; (void)d_ws; (void)ws_size; (void)out_size;
    rnn_fused<<<dim3(kB), dim3(128), 0, stream>>>(
        (const int*)d_in[0], (const int*)d_in[1],
        (const float*)d_in[2], (const float*)d_in[3],
        (const float*)d_in[4], (const float*)d_in[5],
        (const float*)d_in[6], (const float*)d_in[7],
        (float*)d_out);
}

// Round 10
// 452.436 us; speedup vs baseline: 1.1265x; 1.1265x over previous
//
#include <hip/hip_runtime.h>

namespace {
typedef float v2f __attribute__((ext_vector_type(2)));
typedef unsigned u32x2 __attribute__((ext_vector_type(2)));
constexpr int kB = 256;
constexpr int kS = 2048;
constexpr int kV = 10;
constexpr int kE = 32;
constexpr int kH = 64;
constexpr int kO = 10;
constexpr int kT = 16;      // steps per tile
constexpr int kPad = 68;    // LDS row stride in floats (272 B, 16B-aligned)
constexpr int kTiles = kS / kT;   // 128
// Fold tanh's 2x and log2(e) into weights: s = kC*(xw + h.Wh + b), e^{2p} = 2^s
constexpr float kC = 2.885390081777927f;   // 2*log2(e)

__device__ __forceinline__ float step_tanh(float s) {
    s = __builtin_amdgcn_fmed3f(s, -26.f, 26.f);
    float e = __builtin_amdgcn_exp2f(s);
    float r = __builtin_amdgcn_rcpf(e + 1.f);
    return fmaf(-2.f, r, 1.f);              // tanh = 1 - 2/(e^{2p}+1)
}

// p + p[l^32] on the VALU pipe — R8-HW-PROVEN primitive (builtin form).
// permlane32_swap(p,p) returns both post-swap regs; jointly {p, p[l^32]}.
__device__ __forceinline__ float sumswap32(float p) {
    u32x2 r = __builtin_amdgcn_permlane32_swap(__float_as_uint(p),
                                               __float_as_uint(p),
                                               false, false);
    return __uint_as_float(r.x) + __uint_as_float(r.y);
}

// Logits with per-lane FIXED output column o = l%10 (lanes 0..59 active):
// Wd[:,o] lives in 64 VGPRs (wdc) — zero WdT LDS traffic — and the 10 lanes
// of a tl-group read the SAME h-row addresses (LDS broadcast, ~2 clk/instr
// vs 8 for scattered). Halves+ the logits wave's DS-pipe occupancy, which
// was queueing ahead of the chain wave's latency-critical h reads (R10
// theory: DS-pipe contention is part of the chain's fixed cost).
__device__ __forceinline__ void do_logits(const float* __restrict__ hb,
                                          const float (& __restrict__ wdc)[kH],
                                          float bdv,
                                          float* __restrict__ out, int obase, int l)
{
    if (l >= 60) return;
    #pragma unroll
    for (int p = 0; p < 3; ++p) {
        int f = p * 60 + l;                  // flat (t_local, o), 160 total
        if (f < kT * kO) {
            int tl = f / kO;                 // = p*6 + l/10
            const float4* hb4 = reinterpret_cast<const float4*>(hb + tl * kPad);
            float a0 = bdv, a1 = 0.f, a2 = 0.f, a3 = 0.f;
            #pragma unroll
            for (int c = 0; c < kH / 4; ++c) {
                float4 h4 = hb4[c];
                a0 = fmaf(h4.x, wdc[4 * c + 0], a0);
                a1 = fmaf(h4.y, wdc[4 * c + 1], a1);
                a2 = fmaf(h4.z, wdc[4 * c + 2], a2);
                a3 = fmaf(h4.w, wdc[4 * c + 3], a3);
            }
            out[obase + f] = (a0 + a1) + (a2 + a3);   // coalesced (f = p*60+l)
        }
    }
}

// Wave 0: serial recurrence, split-K (R8-proven): each lane reads only its
// 32-wide k-half (8x ds_read_b128, 2-address broadcast) and accumulates that
// half for its own output l (incl. xw) and partner output l^32; halves merge
// via the VALU permlane32_swap. Tail re-associated so (pOwn - pPar) computes
// while the permlane is in flight.
// Wave 1: logits for the previous tile, register-held Wd column (see above).
__global__ __launch_bounds__(128, 1)
void rnn_fused(const int* __restrict__ num1, const int* __restrict__ num2,
               const float* __restrict__ embed, const float* __restrict__ Wx,
               const float* __restrict__ Wh, const float* __restrict__ bias,
               const float* __restrict__ Wd, const float* __restrict__ bd,
               float* __restrict__ out)
{
    const int row = blockIdx.x;   // one sequence per block
    const int tid = threadIdx.x;
    const int w   = tid >> 6;     // 0 = recurrence wave, 1 = logits wave
    const int l   = tid & 63;     // lane owns hidden unit l
    const int lx  = l ^ 32;       // split-K partner lane
    const int kbase = (l >> 5) * 32;       // this lane's k-half

    __shared__ __align__(16) float TT[kV * kV][kH];     // kC*(xw+b), 100 rows
    __shared__ __align__(16) float hbuf[2][kT][kPad];   // double-buffered h history

    v2f whcA2[kH / 4], whcB2[kH / 4];   // kC*Wh k-half cols: own l / partner l^32
    float wdc[kH];                      // wave 1: Wd column l%10
    float bdv = 0.f;
    int idx_next = 0;
    const int lane16 = l & 15;
    const int nb = row * kS;
    const int orow = row * (kS * kO);

    if (w == 0) {
        // ---- one-time setup: input-projection table + Wh half-columns ----
        float wxc[2 * kE];
        #pragma unroll
        for (int k = 0; k < 2 * kE; ++k) wxc[k] = Wx[k * kH + l];  // Wx column l
        float bj = bias[l];
        float t1[kV], t2[kV];
        #pragma unroll
        for (int v = 0; v < kV; ++v) {
            float a0 = 0.f, a1 = 0.f;
            #pragma unroll
            for (int k = 0; k < kE; ++k) {
                float e = embed[v * kE + k];   // lane-uniform -> s_load
                a0 = fmaf(e, wxc[k], a0);
                a1 = fmaf(e, wxc[kE + k], a1);
            }
            t1[v] = a0; t2[v] = a1;
        }
        #pragma unroll
        for (int v1 = 0; v1 < kV; ++v1)
            #pragma unroll
            for (int v2 = 0; v2 < kV; ++v2)
                TT[v1 * kV + v2][l] = kC * (t1[v1] + t2[v2] + bj);
        #pragma unroll
        for (int i = 0; i < kH / 4; ++i) {      // 16 packed pairs per table
            v2f ta, tb;
            ta.x = kC * Wh[(kbase + 2 * i)     * kH + l];
            ta.y = kC * Wh[(kbase + 2 * i + 1) * kH + l];
            tb.x = kC * Wh[(kbase + 2 * i)     * kH + lx];
            tb.y = kC * Wh[(kbase + 2 * i + 1) * kH + lx];
            whcA2[i] = ta; whcB2[i] = tb;
        }
        hbuf[1][kT - 1][l] = 0.f;   // h_{-1}=0: tile 0 broadcast reads this row
        idx_next = num1[nb + lane16] * kV + num2[nb + lane16];   // tile 0 idx
        __builtin_amdgcn_s_setprio(1);   // favor the chain wave in arbitration
    } else {
        const int o = l % kO;            // lanes 60..63 compute but never use
        #pragma unroll
        for (int k = 0; k < kH; ++k) wdc[k] = Wd[k * kO + o];
        bdv = bd[o];
    }
    __syncthreads();

    const float* prevRow = &hbuf[1][kT - 1][0];   // rolling h_{t-1} row

    for (int ti = 0; ti < kTiles; ++ti) {
        if (w == 0) {
            const int idxv = idx_next;
            if (ti + 1 < kTiles) {
                int tt = nb + (ti + 1) * kT + lane16;
                idx_next = num1[tt] * kV + num2[tt];   // prefetch next tile idx
            }
            float* curBase = &hbuf[ti & 1][0][0];
            #pragma unroll 1
            for (int tl = 0; tl < kT; ++tl) {
                const int sidx = __builtin_amdgcn_readlane(idxv, tl); // dyn lane
                const float xwv = TT[sidx][l];   // issued early, consumed late
                const float4* hq = reinterpret_cast<const float4*>(prevRow + kbase);
                float4 q[8];
                #pragma unroll
                for (int c = 0; c < 8; ++c) q[c] = hq[c];   // k-half bcast
                __builtin_amdgcn_sched_barrier(0);          // loads at step head
                v2f o0; o0.x = xwv; o0.y = 0.f;  // xw folded into own-acc init
                v2f o1 = {0.f, 0.f}, r0 = {0.f, 0.f}, r1 = {0.f, 0.f};
                #pragma unroll
                for (int c = 0; c < 8; ++c) {
                    v2f lo; lo.x = q[c].x; lo.y = q[c].y;
                    v2f hi; hi.x = q[c].z; hi.y = q[c].w;
                    o0 = lo * whcA2[2 * c]     + o0;   // own output, own k-half
                    o1 = hi * whcA2[2 * c + 1] + o1;
                    r0 = lo * whcB2[2 * c]     + r0;   // partner output partial
                    r1 = hi * whcB2[2 * c + 1] + r1;
                }
                v2f rv = r0 + r1;  float pPar = rv.x + rv.y;
                float ss = sumswap32(pPar);        // = pPar + pPar[l^32]
                v2f ov = o0 + o1;  float pOwn = ov.x + ov.y;   // incl. xw
                float d  = pOwn - pPar;            // overlaps the permlane
                float hcur = step_tanh(d + ss);
                float* wr = curBase + tl * kPad;
                wr[l] = hcur;              // history row (logits + next bcast)
                prevRow = wr;
            }
        } else if (ti > 0) {
            do_logits(&hbuf[(ti - 1) & 1][0][0], wdc, bdv, out,
                      orow + (ti - 1) * kT * kO, l);
        }
        __syncthreads();   // publish tile ti history / retire tile ti-1 reads
    }
    if (w == 1)
        do_logits(&hbuf[(kTiles - 1) & 1][0][0], wdc, bdv, out,
                  orow + (kS - kT) * kO, l);
}
} // namespace

extern "C" void kernel_launch(void* const* d_in, const int* in_sizes, int n_in,
                              void* d_out, int out_size, void* d_ws, size_t ws_size,
                              hipStream_t stream) {
    (void)in_sizes; (void)n_in; (void)d_ws; (void)ws_size; (void)out_size;
    rnn_fused<<<dim3(kB), dim3(128), 0, stream>>>(
        (const int*)d_in[0], (const int*)d_in[1],
        (const float*)d_in[2], (const float*)d_in[3],
        (const float*)d_in[4], (const float*)d_in[5],
        (const float*)d_in[6], (const float*)d_in[7],
        (float*)d_out);
}

// Round 12
// 452.139 us; speedup vs baseline: 1.1272x; 1.0007x over previous
//
#include <hip/hip_runtime.h>

namespace {
typedef float v2f __attribute__((ext_vector_type(2)));
typedef unsigned u32x2 __attribute__((ext_vector_type(2)));
constexpr int kB = 256;
constexpr int kS = 2048;
constexpr int kV = 10;
constexpr int kE = 32;
constexpr int kH = 64;
constexpr int kO = 10;
constexpr int kT = 16;      // steps per tile
constexpr int kPad = 68;    // LDS row stride in floats (272 B, 16B-aligned)
constexpr int kTiles = kS / kT;   // 128
// Fold tanh's 2x and log2(e) into weights: s = kC*(xw + h.Wh + b), e^{2p} = 2^s
constexpr float kC = 2.885390081777927f;   // 2*log2(e)

// No clamp needed: inputs finite, |s| <~ 23 in practice; and even for huge |s|
// the chain exp2->inf/0, rcp, fma yields exactly +-1 = tanh's limit. Removing
// fmed3 shortens the serial tail by one dependent VALU op.
__device__ __forceinline__ float step_tanh(float s) {
    float e = __builtin_amdgcn_exp2f(s);
    float r = __builtin_amdgcn_rcpf(e + 1.f);
    return fmaf(-2.f, r, 1.f);              // tanh = 1 - 2/(e^{2p}+1)
}

// p + p[l^32] on the VALU pipe — R8-HW-PROVEN primitive (builtin form).
// permlane32_swap(p,p) returns both post-swap regs; jointly {p, p[l^32]}.
__device__ __forceinline__ float sumswap32(float p) {
    u32x2 r = __builtin_amdgcn_permlane32_swap(__float_as_uint(p),
                                               __float_as_uint(p),
                                               false, false);
    return __uint_as_float(r.x) + __uint_as_float(r.y);
}

// Logits with per-lane FIXED output column o = l%10 (lanes 0..59 active):
// Wd[:,o] lives in 64 VGPRs (wdc) — zero WdT LDS traffic — and the 10 lanes
// of a tl-group read the SAME h-row addresses (LDS broadcast). (R10: this
// decontention was worth ~1%.)
__device__ __forceinline__ void do_logits(const float* __restrict__ hb,
                                          const float (& __restrict__ wdc)[kH],
                                          float bdv,
                                          float* __restrict__ out, int obase, int l)
{
    if (l >= 60) return;
    #pragma unroll
    for (int p = 0; p < 3; ++p) {
        int f = p * 60 + l;                  // flat (t_local, o), 160 total
        if (f < kT * kO) {
            int tl = f / kO;                 // = p*6 + l/10
            const float4* hb4 = reinterpret_cast<const float4*>(hb + tl * kPad);
            float a0 = bdv, a1 = 0.f, a2 = 0.f, a3 = 0.f;
            #pragma unroll
            for (int c = 0; c < kH / 4; ++c) {
                float4 h4 = hb4[c];
                a0 = fmaf(h4.x, wdc[4 * c + 0], a0);
                a1 = fmaf(h4.y, wdc[4 * c + 1], a1);
                a2 = fmaf(h4.z, wdc[4 * c + 2], a2);
                a3 = fmaf(h4.w, wdc[4 * c + 3], a3);
            }
            out[obase + f] = (a0 + a1) + (a2 + a3);   // coalesced (f = p*60+l)
        }
    }
}

// Wave 0: serial recurrence, split-K (R8-proven): each lane reads only its
// 32-wide k-half (8x ds_read_b128, 2-address broadcast) and accumulates that
// half for its own output l (incl. xw) and partner output l^32; halves merge
// via the VALU permlane32_swap.
// R11 change: NO sched_barrier after the load batch — let the scheduler
// interleave ds_read/pk_fma with counted lgkmcnt so the first FMA starts on
// load-0's return instead of the whole batch's drain (R10 had ~115cy/step
// unexplained; batch-drain serialization is the prime suspect).
// Wave 1: logits for the previous tile, register-held Wd column.
__global__ __launch_bounds__(128, 1)
void rnn_fused(const int* __restrict__ num1, const int* __restrict__ num2,
               const float* __restrict__ embed, const float* __restrict__ Wx,
               const float* __restrict__ Wh, const float* __restrict__ bias,
               const float* __restrict__ Wd, const float* __restrict__ bd,
               float* __restrict__ out)
{
    const int row = blockIdx.x;   // one sequence per block
    const int tid = threadIdx.x;
    const int w   = tid >> 6;     // 0 = recurrence wave, 1 = logits wave
    const int l   = tid & 63;     // lane owns hidden unit l
    const int lx  = l ^ 32;       // split-K partner lane
    const int kbase = (l >> 5) * 32;       // this lane's k-half

    __shared__ __align__(16) float TT[kV * kV][kH];     // kC*(xw+b), 100 rows
    __shared__ __align__(16) float hbuf[2][kT][kPad];   // double-buffered h history

    v2f whcA2[kH / 4], whcB2[kH / 4];   // kC*Wh k-half cols: own l / partner l^32
    float wdc[kH];                      // wave 1: Wd column l%10
    float bdv = 0.f;
    int idx_next = 0;
    const int lane16 = l & 15;
    const int nb = row * kS;
    const int orow = row * (kS * kO);

    if (w == 0) {
        // ---- one-time setup: input-projection table + Wh half-columns ----
        float wxc[2 * kE];
        #pragma unroll
        for (int k = 0; k < 2 * kE; ++k) wxc[k] = Wx[k * kH + l];  // Wx column l
        float bj = bias[l];
        float t1[kV], t2[kV];
        #pragma unroll
        for (int v = 0; v < kV; ++v) {
            float a0 = 0.f, a1 = 0.f;
            #pragma unroll
            for (int k = 0; k < kE; ++k) {
                float e = embed[v * kE + k];   // lane-uniform -> s_load
                a0 = fmaf(e, wxc[k], a0);
                a1 = fmaf(e, wxc[kE + k], a1);
            }
            t1[v] = a0; t2[v] = a1;
        }
        #pragma unroll
        for (int v1 = 0; v1 < kV; ++v1)
            #pragma unroll
            for (int v2 = 0; v2 < kV; ++v2)
                TT[v1 * kV + v2][l] = kC * (t1[v1] + t2[v2] + bj);
        #pragma unroll
        for (int i = 0; i < kH / 4; ++i) {      // 16 packed pairs per table
            v2f ta, tb;
            ta.x = kC * Wh[(kbase + 2 * i)     * kH + l];
            ta.y = kC * Wh[(kbase + 2 * i + 1) * kH + l];
            tb.x = kC * Wh[(kbase + 2 * i)     * kH + lx];
            tb.y = kC * Wh[(kbase + 2 * i + 1) * kH + lx];
            whcA2[i] = ta; whcB2[i] = tb;
        }
        hbuf[1][kT - 1][l] = 0.f;   // h_{-1}=0: tile 0 broadcast reads this row
        idx_next = num1[nb + lane16] * kV + num2[nb + lane16];   // tile 0 idx
        __builtin_amdgcn_s_setprio(1);   // favor the chain wave in arbitration
    } else {
        const int o = l % kO;            // lanes 60..63 compute but never use
        #pragma unroll
        for (int k = 0; k < kH; ++k) wdc[k] = Wd[k * kO + o];
        bdv = bd[o];
    }
    __syncthreads();

    const float* prevRow = &hbuf[1][kT - 1][0];   // rolling h_{t-1} row

    for (int ti = 0; ti < kTiles; ++ti) {
        if (w == 0) {
            const int idxv = idx_next;
            if (ti + 1 < kTiles) {
                int tt = nb + (ti + 1) * kT + lane16;
                idx_next = num1[tt] * kV + num2[tt];   // prefetch next tile idx
            }
            float* curBase = &hbuf[ti & 1][0][0];
            #pragma unroll 1
            for (int tl = 0; tl < kT; ++tl) {
                const int sidx = __builtin_amdgcn_readlane(idxv, tl); // dyn lane
                const float xwv = TT[sidx][l];   // issued first, returns first
                const float4* hq = reinterpret_cast<const float4*>(prevRow + kbase);
                float4 q[8];
                #pragma unroll
                for (int c = 0; c < 8; ++c) q[c] = hq[c];   // k-half bcast
                // (no sched_barrier: allow ds_read/pk_fma interleave)
                v2f o0; o0.x = xwv; o0.y = 0.f;  // xw folded into own-acc init
                v2f o1 = {0.f, 0.f}, r0 = {0.f, 0.f}, r1 = {0.f, 0.f};
                #pragma unroll
                for (int c = 0; c < 8; ++c) {
                    v2f lo; lo.x = q[c].x; lo.y = q[c].y;
                    v2f hi; hi.x = q[c].z; hi.y = q[c].w;
                    o0 = lo * whcA2[2 * c]     + o0;   // own output, own k-half
                    o1 = hi * whcA2[2 * c + 1] + o1;
                    r0 = lo * whcB2[2 * c]     + r0;   // partner output partial
                    r1 = hi * whcB2[2 * c + 1] + r1;
                }
                v2f rv = r0 + r1;  float pPar = rv.x + rv.y;
                float ss = sumswap32(pPar);        // = pPar + pPar[l^32]
                v2f ov = o0 + o1;  float pOwn = ov.x + ov.y;   // incl. xw
                float d  = pOwn - pPar;            // overlaps the permlane
                float hcur = step_tanh(d + ss);
                float* wr = curBase + tl * kPad;
                wr[l] = hcur;              // history row (logits + next bcast)
                prevRow = wr;
            }
        } else if (ti > 0) {
            do_logits(&hbuf[(ti - 1) & 1][0][0], wdc, bdv, out,
                      orow + (ti - 1) * kT * kO, l);
        }
        __syncthreads();   // publish tile ti history / retire tile ti-1 reads
    }
    if (w == 1)
        do_logits(&hbuf[(kTiles - 1) & 1][0][0], wdc, bdv, out,
                  orow + (kS - kT) * kO, l);
}
} // namespace

extern "C" void kernel_launch(void* const* d_in, const int* in_sizes, int n_in,
                              void* d_out, int out_size, void* d_ws, size_t ws_size,
                              hipStream_t stream) {
    (void)in_sizes; (void)n_in; (void)d_ws; (void)ws_size; (void)out_size;
    rnn_fused<<<dim3(kB), dim3(128), 0, stream>>>(
        (const int*)d_in[0], (const int*)d_in[1],
        (const float*)d_in[2], (const float*)d_in[3],
        (const float*)d_in[4], (const float*)d_in[5],
        (const float*)d_in[6], (const float*)d_in[7],
        (float*)d_out);
}

// Round 13
// 419.934 us; speedup vs baseline: 1.2137x; 1.0767x over previous
//
#include <hip/hip_runtime.h>

namespace {
typedef float v2f __attribute__((ext_vector_type(2)));
typedef unsigned u32x2 __attribute__((ext_vector_type(2)));
constexpr int kB = 256;
constexpr int kS = 2048;
constexpr int kV = 10;
constexpr int kE = 32;
constexpr int kH = 64;
constexpr int kO = 10;
constexpr int kT = 16;      // steps per tile
constexpr int kPad = 68;    // LDS row stride in floats (272 B, 16B-aligned)
constexpr int kTiles = kS / kT;   // 128
// Fold tanh's 2x and log2(e) into weights: s = kC*(xw + h.Wh + b), e^{2p} = 2^s
constexpr float kC = 2.885390081777927f;   // 2*log2(e)

// No clamp needed (R12-proven): even for huge |s| the chain exp2->inf/0, rcp,
// fma yields exactly +-1 = tanh's limit.
__device__ __forceinline__ float step_tanh(float s) {
    float e = __builtin_amdgcn_exp2f(s);
    float r = __builtin_amdgcn_rcpf(e + 1.f);
    return fmaf(-2.f, r, 1.f);              // tanh = 1 - 2/(e^{2p}+1)
}

// R8-HW-proven VALU half-exchange; returns both post-swap registers, which
// jointly hold {p, p[l^32]} at every lane.
__device__ __forceinline__ u32x2 plswap(float p) {
    return __builtin_amdgcn_permlane32_swap(__float_as_uint(p),
                                            __float_as_uint(p),
                                            false, false);
}

// Logits with per-lane FIXED output column o = l%10 (lanes 0..59 active):
// Wd[:,o] lives in 64 VGPRs — zero Wd LDS traffic — and the 10 lanes of a
// tl-group read the SAME h-row addresses (LDS broadcast). (R10: small win.)
__device__ __forceinline__ void do_logits(const float* __restrict__ hb,
                                          const float (& __restrict__ wdc)[kH],
                                          float bdv,
                                          float* __restrict__ out, int obase, int l)
{
    if (l >= 60) return;
    #pragma unroll
    for (int p = 0; p < 3; ++p) {
        int f = p * 60 + l;                  // flat (t_local, o), 160 total
        if (f < kT * kO) {
            int tl = f / kO;                 // = p*6 + l/10
            const float4* hb4 = reinterpret_cast<const float4*>(hb + tl * kPad);
            float a0 = bdv, a1 = 0.f, a2 = 0.f, a3 = 0.f;
            #pragma unroll
            for (int c = 0; c < kH / 4; ++c) {
                float4 h4 = hb4[c];
                a0 = fmaf(h4.x, wdc[4 * c + 0], a0);
                a1 = fmaf(h4.y, wdc[4 * c + 1], a1);
                a2 = fmaf(h4.z, wdc[4 * c + 2], a2);
                a3 = fmaf(h4.w, wdc[4 * c + 3], a3);
            }
            out[obase + f] = (a0 + a1) + (a2 + a3);   // coalesced (f = p*60+l)
        }
    }
}

// Wave 0: serial recurrence, split-K (R8-proven): each lane reads only its
// 32-wide k-half (8x ds_read_b128 broadcast), accumulates own output l
// (incl. xw) + partner output l^32; halves merge via permlane32_swap.
// R13 instruction diet: (1) FULL unroll of the 16-step loop -> all LDS
// addresses are base+immediate, no per-step pointer math; (2) tile-head xw
// prefetch burst (latency hides under step-0's h-load wait; removes a DS
// read + readlane from every step); (3) setup-time probe of the permlane
// convention -> exact 2-op combine (cndmask + add) instead of add+sub+add.
// Wave 1: logits for the previous tile, register-held Wd column.
__global__ __launch_bounds__(128, 1)
void rnn_fused(const int* __restrict__ num1, const int* __restrict__ num2,
               const float* __restrict__ embed, const float* __restrict__ Wx,
               const float* __restrict__ Wh, const float* __restrict__ bias,
               const float* __restrict__ Wd, const float* __restrict__ bd,
               float* __restrict__ out)
{
    const int row = blockIdx.x;   // one sequence per block
    const int tid = threadIdx.x;
    const int w   = tid >> 6;     // 0 = recurrence wave, 1 = logits wave
    const int l   = tid & 63;     // lane owns hidden unit l
    const int lx  = l ^ 32;       // split-K partner lane
    const int kbase = (l >> 5) * 32;       // this lane's k-half

    __shared__ __align__(16) float TT[kV * kV][kH];     // kC*(xw+b), 100 rows
    __shared__ __align__(16) float hbuf[2][kT][kPad];   // double-buffered h history

    v2f whcA2[kH / 4], whcB2[kH / 4];   // kC*Wh k-half cols: own l / partner l^32
    float wdc[kH];                      // wave 1: Wd column l%10
    float bdv = 0.f;
    int idx_next = 0;
    bool selx = false;                  // permlane convention (probed)
    const int lane16 = l & 15;
    const int nb = row * kS;
    const int orow = row * (kS * kO);

    if (w == 0) {
        // ---- one-time setup: input-projection table + Wh half-columns ----
        float wxc[2 * kE];
        #pragma unroll
        for (int k = 0; k < 2 * kE; ++k) wxc[k] = Wx[k * kH + l];  // Wx column l
        float bj = bias[l];
        float t1[kV], t2[kV];
        #pragma unroll
        for (int v = 0; v < kV; ++v) {
            float a0 = 0.f, a1 = 0.f;
            #pragma unroll
            for (int k = 0; k < kE; ++k) {
                float e = embed[v * kE + k];   // lane-uniform -> s_load
                a0 = fmaf(e, wxc[k], a0);
                a1 = fmaf(e, wxc[kE + k], a1);
            }
            t1[v] = a0; t2[v] = a1;
        }
        #pragma unroll
        for (int v1 = 0; v1 < kV; ++v1)
            #pragma unroll
            for (int v2 = 0; v2 < kV; ++v2)
                TT[v1 * kV + v2][l] = kC * (t1[v1] + t2[v2] + bj);
        #pragma unroll
        for (int i = 0; i < kH / 4; ++i) {      // 16 packed pairs per table
            v2f ta, tb;
            ta.x = kC * Wh[(kbase + 2 * i)     * kH + l];
            ta.y = kC * Wh[(kbase + 2 * i + 1) * kH + l];
            tb.x = kC * Wh[(kbase + 2 * i)     * kH + lx];
            tb.y = kC * Wh[(kbase + 2 * i + 1) * kH + lx];
            whcA2[i] = ta; whcB2[i] = tb;
        }
        // probe which swap output holds the PARTNER value (per-lane robust)
        {
            u32x2 pr = plswap((float)l);
            selx = (__uint_as_float(pr.x) == (float)lx);
        }
        hbuf[1][kT - 1][l] = 0.f;   // h_{-1}=0: tile 0 broadcast reads this row
        idx_next = num1[nb + lane16] * kV + num2[nb + lane16];   // tile 0 idx
        __builtin_amdgcn_s_setprio(1);   // favor the chain wave in arbitration
    } else {
        const int o = l % kO;            // lanes 60..63 compute but never use
        #pragma unroll
        for (int k = 0; k < kH; ++k) wdc[k] = Wd[k * kO + o];
        bdv = bd[o];
    }
    __syncthreads();

    for (int ti = 0; ti < kTiles; ++ti) {
        if (w == 0) {
            const int idxv = idx_next;
            if (ti + 1 < kTiles) {
                int tt = nb + (ti + 1) * kT + lane16;
                idx_next = num1[tt] * kV + num2[tt];   // prefetch next tile idx
            }
            float* curBase = &hbuf[ti & 1][0][0];
            const float* prevLast = &hbuf[(ti & 1) ^ 1][kT - 1][0];
            // step-0 h loads FIRST (longest latency)...
            float4 q[8];
            {
                const float4* hq0 =
                    reinterpret_cast<const float4*>(prevLast + kbase);
                #pragma unroll
                for (int c = 0; c < 8; ++c) q[c] = hq0[c];
            }
            // ...then the tile's xw burst; its latency hides under the q wait
            float xwr[kT];
            #pragma unroll
            for (int t2 = 0; t2 < kT; ++t2)
                xwr[t2] = TT[__builtin_amdgcn_readlane(idxv, t2)][l];
            #pragma unroll
            for (int tl = 0; tl < kT; ++tl) {
                v2f o0; o0.x = xwr[tl]; o0.y = 0.f;  // xw folded into acc init
                v2f o1 = {0.f, 0.f}, r0 = {0.f, 0.f}, r1 = {0.f, 0.f};
                #pragma unroll
                for (int c = 0; c < 8; ++c) {
                    v2f lo; lo.x = q[c].x; lo.y = q[c].y;
                    v2f hi; hi.x = q[c].z; hi.y = q[c].w;
                    o0 = lo * whcA2[2 * c]     + o0;   // own output, own k-half
                    o1 = hi * whcA2[2 * c + 1] + o1;
                    r0 = lo * whcB2[2 * c]     + r0;   // partner output partial
                    r1 = hi * whcB2[2 * c + 1] + r1;
                }
                v2f rv = r0 + r1;  float pPar = rv.x + rv.y;
                u32x2 sw = plswap(pPar);
                float oth = selx ? __uint_as_float(sw.x)
                                 : __uint_as_float(sw.y);   // exact partner
                v2f ov = o0 + o1;  float pOwn = ov.x + ov.y;   // incl. xw
                float hcur = step_tanh(pOwn + oth);
                curBase[tl * kPad + l] = hcur;   // publish h_t (row tl)
                if (tl + 1 < kT) {               // next step's h loads
                    const float4* hqn = reinterpret_cast<const float4*>(
                        curBase + tl * kPad + kbase);
                    #pragma unroll
                    for (int c = 0; c < 8; ++c) q[c] = hqn[c];
                }
            }
        } else if (ti > 0) {
            do_logits(&hbuf[(ti - 1) & 1][0][0], wdc, bdv, out,
                      orow + (ti - 1) * kT * kO, l);
        }
        __syncthreads();   // publish tile ti history / retire tile ti-1 reads
    }
    if (w == 1)
        do_logits(&hbuf[(kTiles - 1) & 1][0][0], wdc, bdv, out,
                  orow + (kS - kT) * kO, l);
}
} // namespace

extern "C" void kernel_launch(void* const* d_in, const int* in_sizes, int n_in,
                              void* d_out, int out_size, void* d_ws, size_t ws_size,
                              hipStream_t stream) {
    (void)in_sizes; (void)n_in; (void)d_ws; (void)ws_size; (void)out_size;
    rnn_fused<<<dim3(kB), dim3(128), 0, stream>>>(
        (const int*)d_in[0], (const int*)d_in[1],
        (const float*)d_in[2], (const float*)d_in[3],
        (const float*)d_in[4], (const float*)d_in[5],
        (const float*)d_in[6], (const float*)d_in[7],
        (float*)d_out);
}

// Round 14
// 414.894 us; speedup vs baseline: 1.2284x; 1.0121x over previous
//
#include <hip/hip_runtime.h>

namespace {
typedef float v2f __attribute__((ext_vector_type(2)));
typedef unsigned u32x2 __attribute__((ext_vector_type(2)));
constexpr int kB = 256;
constexpr int kS = 2048;
constexpr int kV = 10;
constexpr int kE = 32;
constexpr int kH = 64;
constexpr int kO = 10;
constexpr int kT = 32;      // steps per tile (R14: 16 -> 32, half the barriers)
constexpr int kPad = 68;    // LDS row stride in floats (272 B, 16B-aligned)
constexpr int kTiles = kS / kT;   // 64
// Fold tanh's 2x and log2(e) into weights: s = kC*(xw + h.Wh + b), e^{2p} = 2^s
constexpr float kC = 2.885390081777927f;   // 2*log2(e)

// No clamp needed (R12-proven): even for huge |s| the chain exp2->inf/0, rcp,
// fma yields exactly +-1 = tanh's limit.
__device__ __forceinline__ float step_tanh(float s) {
    float e = __builtin_amdgcn_exp2f(s);
    float r = __builtin_amdgcn_rcpf(e + 1.f);
    return fmaf(-2.f, r, 1.f);              // tanh = 1 - 2/(e^{2p}+1)
}

// R8-HW-proven VALU half-exchange; returns both post-swap registers, which
// jointly hold {p, p[l^32]} at every lane.
__device__ __forceinline__ u32x2 plswap(float p) {
    return __builtin_amdgcn_permlane32_swap(__float_as_uint(p),
                                            __float_as_uint(p),
                                            false, false);
}

// Logits with per-lane FIXED output column o = l%10 (lanes 0..59 active):
// Wd[:,o] lives in 64 VGPRs — zero Wd LDS traffic — and the 10 lanes of a
// tl-group read the SAME h-row addresses (LDS broadcast). kT=32 -> 6 passes.
__device__ __forceinline__ void do_logits(const float* __restrict__ hb,
                                          const float (& __restrict__ wdc)[kH],
                                          float bdv,
                                          float* __restrict__ out, int obase, int l)
{
    if (l >= 60) return;
    #pragma unroll
    for (int p = 0; p < 6; ++p) {
        int f = p * 60 + l;                  // flat (t_local, o), 320 total
        if (f < kT * kO) {
            int tl = f / kO;
            const float4* hb4 = reinterpret_cast<const float4*>(hb + tl * kPad);
            float a0 = bdv, a1 = 0.f, a2 = 0.f, a3 = 0.f;
            #pragma unroll
            for (int c = 0; c < kH / 4; ++c) {
                float4 h4 = hb4[c];
                a0 = fmaf(h4.x, wdc[4 * c + 0], a0);
                a1 = fmaf(h4.y, wdc[4 * c + 1], a1);
                a2 = fmaf(h4.z, wdc[4 * c + 2], a2);
                a3 = fmaf(h4.w, wdc[4 * c + 3], a3);
            }
            out[obase + f] = (a0 + a1) + (a2 + a3);   // coalesced (f = p*60+l)
        }
    }
}

// Wave 0: serial recurrence, split-K (R8-proven): each lane reads only its
// 32-wide k-half (8x ds_read_b128 broadcast), accumulates own output l
// (incl. xw) + partner output l^32; halves merge via permlane32_swap with the
// setup-probed exact combine (R13). Fully unrolled steps (R13).
// R14: kT=32 (half the barriers) + PRE-BARRIER prefetch of the next tile's
// step-0 h reads (row kT-1 just written by this same wave -> in-order DS pipe
// makes the read legal without the barrier) and next xw burst, so their
// latency overlaps the barrier wait instead of serializing after it.
// Wave 1: logits for the previous tile, register-held Wd column.
__global__ __launch_bounds__(128, 1)
void rnn_fused(const int* __restrict__ num1, const int* __restrict__ num2,
               const float* __restrict__ embed, const float* __restrict__ Wx,
               const float* __restrict__ Wh, const float* __restrict__ bias,
               const float* __restrict__ Wd, const float* __restrict__ bd,
               float* __restrict__ out)
{
    const int row = blockIdx.x;   // one sequence per block
    const int tid = threadIdx.x;
    const int w   = tid >> 6;     // 0 = recurrence wave, 1 = logits wave
    const int l   = tid & 63;     // lane owns hidden unit l
    const int lx  = l ^ 32;       // split-K partner lane
    const int kbase = (l >> 5) * 32;       // this lane's k-half

    __shared__ __align__(16) float TT[kV * kV][kH];     // kC*(xw+b), 100 rows
    __shared__ __align__(16) float hbuf[2][kT][kPad];   // double-buffered h history

    v2f whcA2[kH / 4], whcB2[kH / 4];   // kC*Wh k-half cols: own l / partner l^32
    float wdc[kH];                      // wave 1: Wd column l%10
    float bdv = 0.f;
    int idx_next = 0;
    bool selx = false;                  // permlane convention (probed)
    const int lane32 = l & 31;          // 32 idx slots per tile now
    const int nb = row * kS;
    const int orow = row * (kS * kO);

    if (w == 0) {
        // ---- one-time setup: input-projection table + Wh half-columns ----
        float wxc[2 * kE];
        #pragma unroll
        for (int k = 0; k < 2 * kE; ++k) wxc[k] = Wx[k * kH + l];  // Wx column l
        float bj = bias[l];
        float t1[kV], t2[kV];
        #pragma unroll
        for (int v = 0; v < kV; ++v) {
            float a0 = 0.f, a1 = 0.f;
            #pragma unroll
            for (int k = 0; k < kE; ++k) {
                float e = embed[v * kE + k];   // lane-uniform -> s_load
                a0 = fmaf(e, wxc[k], a0);
                a1 = fmaf(e, wxc[kE + k], a1);
            }
            t1[v] = a0; t2[v] = a1;
        }
        #pragma unroll
        for (int v1 = 0; v1 < kV; ++v1)
            #pragma unroll
            for (int v2 = 0; v2 < kV; ++v2)
                TT[v1 * kV + v2][l] = kC * (t1[v1] + t2[v2] + bj);
        #pragma unroll
        for (int i = 0; i < kH / 4; ++i) {      // 16 packed pairs per table
            v2f ta, tb;
            ta.x = kC * Wh[(kbase + 2 * i)     * kH + l];
            ta.y = kC * Wh[(kbase + 2 * i + 1) * kH + l];
            tb.x = kC * Wh[(kbase + 2 * i)     * kH + lx];
            tb.y = kC * Wh[(kbase + 2 * i + 1) * kH + lx];
            whcA2[i] = ta; whcB2[i] = tb;
        }
        // probe which swap output holds the PARTNER value (per-lane robust)
        {
            u32x2 pr = plswap((float)l);
            selx = (__uint_as_float(pr.x) == (float)lx);
        }
        hbuf[1][kT - 1][l] = 0.f;   // h_{-1}=0: tile 0 prefetch reads this row
        idx_next = num1[nb + lane32] * kV + num2[nb + lane32];   // tile 0 idx
        __builtin_amdgcn_s_setprio(1);   // favor the chain wave in arbitration
    } else {
        const int o = l % kO;            // lanes 60..63 compute but never use
        #pragma unroll
        for (int k = 0; k < kH; ++k) wdc[k] = Wd[k * kO + o];
        bdv = bd[o];
    }
    __syncthreads();

    float4 q[8];          // in-flight h quads (step-0 of each tile prefetched)
    float xwr[kT];        // tile's xw values (prefetched burst)
    if (w == 0) {
        // peel: tile-0 prefetch (q from zeroed row, xw burst for tile 0)
        const float4* hq0 =
            reinterpret_cast<const float4*>(&hbuf[1][kT - 1][0] + kbase);
        #pragma unroll
        for (int c = 0; c < 8; ++c) q[c] = hq0[c];
        #pragma unroll
        for (int t2 = 0; t2 < kT; ++t2)
            xwr[t2] = TT[__builtin_amdgcn_readlane(idx_next, t2)][l];
    }

    for (int ti = 0; ti < kTiles; ++ti) {
        if (w == 0) {
            if (ti + 1 < kTiles) {
                int tt = nb + (ti + 1) * kT + lane32;
                idx_next = num1[tt] * kV + num2[tt];   // prefetch next tile idx
            }
            float* curBase = &hbuf[ti & 1][0][0];
            #pragma unroll
            for (int tl = 0; tl < kT; ++tl) {
                v2f o0; o0.x = xwr[tl]; o0.y = 0.f;  // xw folded into acc init
                v2f o1 = {0.f, 0.f}, r0 = {0.f, 0.f}, r1 = {0.f, 0.f};
                #pragma unroll
                for (int c = 0; c < 8; ++c) {
                    v2f lo; lo.x = q[c].x; lo.y = q[c].y;
                    v2f hi; hi.x = q[c].z; hi.y = q[c].w;
                    o0 = lo * whcA2[2 * c]     + o0;   // own output, own k-half
                    o1 = hi * whcA2[2 * c + 1] + o1;
                    r0 = lo * whcB2[2 * c]     + r0;   // partner output partial
                    r1 = hi * whcB2[2 * c + 1] + r1;
                }
                v2f rv = r0 + r1;  float pPar = rv.x + rv.y;
                u32x2 sw = plswap(pPar);
                float oth = selx ? __uint_as_float(sw.x)
                                 : __uint_as_float(sw.y);   // exact partner
                v2f ov = o0 + o1;  float pOwn = ov.x + ov.y;   // incl. xw
                float hcur = step_tanh(pOwn + oth);
                curBase[tl * kPad + l] = hcur;   // publish h_t (row tl)
                if (tl + 1 < kT) {               // next step's h loads
                    const float4* hqn = reinterpret_cast<const float4*>(
                        curBase + tl * kPad + kbase);
                    #pragma unroll
                    for (int c = 0; c < 8; ++c) q[c] = hqn[c];
                }
            }
            // ---- PRE-BARRIER prefetch for tile ti+1 ----
            // q: row kT-1 of curBase, written above by THIS wave (in-order DS
            // pipe -> read sees the write; barrier not needed for this).
            // xw burst: TT is read-only. Latencies overlap the barrier wait.
            {
                const float4* hqn = reinterpret_cast<const float4*>(
                    curBase + (kT - 1) * kPad + kbase);
                #pragma unroll
                for (int c = 0; c < 8; ++c) q[c] = hqn[c];
                if (ti + 1 < kTiles) {
                    #pragma unroll
                    for (int t2 = 0; t2 < kT; ++t2)
                        xwr[t2] = TT[__builtin_amdgcn_readlane(idx_next, t2)][l];
                }
            }
        } else if (ti > 0) {
            do_logits(&hbuf[(ti - 1) & 1][0][0], wdc, bdv, out,
                      orow + (ti - 1) * kT * kO, l);
        }
        __syncthreads();   // publish tile ti history / retire tile ti-1 reads
    }
    if (w == 1)
        do_logits(&hbuf[(kTiles - 1) & 1][0][0], wdc, bdv, out,
                  orow + (kS - kT) * kO, l);
}
} // namespace

extern "C" void kernel_launch(void* const* d_in, const int* in_sizes, int n_in,
                              void* d_out, int out_size, void* d_ws, size_t ws_size,
                              hipStream_t stream) {
    (void)in_sizes; (void)n_in; (void)d_ws; (void)ws_size; (void)out_size;
    rnn_fused<<<dim3(kB), dim3(128), 0, stream>>>(
        (const int*)d_in[0], (const int*)d_in[1],
        (const float*)d_in[2], (const float*)d_in[3],
        (const float*)d_in[4], (const float*)d_in[5],
        (const float*)d_in[6], (const float*)d_in[7],
        (float*)d_out);
}